// Round 8
// baseline (269.714 us; speedup 1.0000x reference)
//
#include <hip/hip_runtime.h>
#include <hip/hip_bf16.h>

// Attention fwd with materialized p_attn.
// B=16, S=2048, D=64, f32 in/out. d_out = [out (B,S,D) | p_attn (B,S,S)] f32.
#define BN 16
#define SN 2048
#define DN 64
#define QB 16
#define NCHUNK (SN / 32)   // 64 chunks of 32 keys; one wave covers all of them

#define SC_L2E 0.18033688011112042f   // 0.125 * log2(e)
#define BI_L2E 11.541560327111707f    // 8 * log2(e): p~ = exp(s - 8)

typedef __attribute__((ext_vector_type(8))) short bf16x8;
typedef __attribute__((ext_vector_type(4))) short bf16x4;
typedef __attribute__((ext_vector_type(4))) float f32x4;
typedef __attribute__((ext_vector_type(4))) int   i32x4;

static __device__ __forceinline__ short f2bf(float f) {
    __hip_bfloat16 h = __float2bfloat16(f);
    union { __hip_bfloat16 h; short s; } u; u.h = h;
    return u.s;
}
static __device__ __forceinline__ unsigned pk2(float lo, float hi) {
    return ((unsigned)(unsigned short)f2bf(lo)) |
           (((unsigned)(unsigned short)f2bf(hi)) << 16);
}
static __device__ __forceinline__ float fast_exp2(float x) {
#if __has_builtin(__builtin_amdgcn_exp2f)
    return __builtin_amdgcn_exp2f(x);
#else
    return exp2f(x);
#endif
}

// ---- prep: K->bf16 [B][S][D]; V->bf16 transposed [B][D][S]; mask->f32 bias ----
__global__ __launch_bounds__(256)
void prep_kv(const float* __restrict__ K, const float* __restrict__ V,
             const int* __restrict__ M,
             short* __restrict__ Kp, short* __restrict__ Vt, float* __restrict__ Mf)
{
    __shared__ short vt[64][68];
    const int b  = blockIdx.x >> 5;
    const int s0 = (blockIdx.x & 31) << 6;
    const int tid = threadIdx.x;
    const int sr = tid >> 4;
    const int dc = (tid & 15) << 2;
    const float* Kb = K + ((size_t)b * SN + s0) * DN;
    const float* Vb = V + ((size_t)b * SN + s0) * DN;
    short* Kpb = Kp + ((size_t)b * SN + s0) * DN;
    #pragma unroll
    for (int i = 0; i < 4; ++i) {
        const int s = sr + i * 16;
        f32x4 kv = *(const f32x4*)(Kb + (size_t)s * DN + dc);
        f32x4 vv = *(const f32x4*)(Vb + (size_t)s * DN + dc);
        bf16x4 k4, v4;
        #pragma unroll
        for (int j = 0; j < 4; ++j) { k4[j] = f2bf(kv[j]); v4[j] = f2bf(vv[j]); }
        *(bf16x4*)(Kpb + (size_t)s * DN + dc) = k4;
        *(bf16x4*)&vt[s][dc] = v4;
    }
    if (tid < 64) {
        const int m = M[(size_t)b * SN + s0 + tid];
        Mf[(size_t)b * SN + s0 + tid] = m ? -BI_L2E : -1e9f;
    }
    __syncthreads();
    const int d  = tid >> 2;
    const int sg = (tid & 3) << 4;
    short* dst = Vt + ((size_t)b * DN + d) * SN + s0 + sg;
    bf16x8 w0, w1;
    #pragma unroll
    for (int j = 0; j < 8; ++j) { w0[j] = vt[sg + j][d]; w1[j] = vt[sg + 8 + j][d]; }
    *(bf16x8*)dst = w0;
    *(bf16x8*)(dst + 8) = w1;
}

// ---- fused attention: wave-independent, zero LDS, zero barriers ----
// One wave owns one 16-q tile x all 2048 keys.
// Pass A: swapped QK^T (mfma(K,Q)) + exp -> row sums (lane-local, shfl reduce).
// Pass B: QK^T AGAIN + exp -> scale -> plain f32x4 stores (spread over 64 chunks)
//         + PV mfma. PV A-operand = packed exp quads IN PLACE: mfma contracts by
//         slot, so A and B use the same k-permutation pi(lg,j) = (j<4 ? 4lg+j :
//         16+4lg+j-4); V^T quads loaded at k=4lg and k=16+4lg to match.
template <int PRE>
__global__ __launch_bounds__(256, 4)
void attn_fused(const float* __restrict__ Q, const float* __restrict__ K,
                const float* __restrict__ V, const int* __restrict__ M,
                const short* __restrict__ Kp, const short* __restrict__ Vt,
                const float* __restrict__ Mf, float* __restrict__ out)
{
    const int tid = threadIdx.x;
    const int wv = tid >> 6, ln = tid & 63;
    const int lq = ln & 15, lg = ln >> 4;

    // XCD-bijective swizzle: 512 blocks / 8 XCDs = 64 blocks each -> 2 batches/XCD.
    const int lb = ((blockIdx.x & 7) << 6) | (blockIdx.x >> 3);
    const int t  = (lb << 2) | wv;            // q-tile index in [0, 2048)
    const int bb = t >> 7;
    const int q0 = (t & 127) << 4;

    const float* Qb = Q + ((size_t)bb * SN + q0) * DN;
    const float* Kb = K + (size_t)bb * SN * DN;
    const float* Vb = V + (size_t)bb * SN * DN;
    const short* Kpb = Kp + (size_t)bb * SN * DN;
    const short* Vtb = Vt + (size_t)bb * DN * SN;
    const int*   Mb = M + (size_t)bb * SN;
    const float* Fb = Mf + (size_t)bb * SN;
    float* out_o = out + ((size_t)bb * SN + q0) * DN;
    float* out_p = out + (size_t)BN * SN * DN + ((size_t)bb * SN + q0) * SN;

    // ---- Q fragment (B-operand of swapped QK^T): Q[col=lq][d=8*lg+j] ----
    bf16x8 qf0, qf1;
    {
        const float* src = Qb + lq * DN + lg * 8;
        f32x4 a = *(const f32x4*)src;
        f32x4 b = *(const f32x4*)(src + 4);
        f32x4 c = *(const f32x4*)(src + 32);
        f32x4 d = *(const f32x4*)(src + 36);
        #pragma unroll
        for (int j = 0; j < 4; ++j) {
            qf0[j] = f2bf(a[j]); qf0[4 + j] = f2bf(b[j]);
            qf1[j] = f2bf(c[j]); qf1[4 + j] = f2bf(d[j]);
        }
    }

    const short* kptr = Kpb + (size_t)lq * DN + lg * 8;   // + c*2048 per chunk
    const float* fptr = Fb + 4 * lg;                      // + c*32 (and +16)

    // ================= pass A: row sums only =================
    float lsum = 0.f;
    #pragma unroll 2
    for (int c = 0; c < NCHUNK; ++c) {
        bf16x8 kf0, kf1, kf2, kf3;
        f32x4 b0, b1;
        if constexpr (PRE) {
            kf0 = *(const bf16x8*)(kptr + c * 2048);
            kf1 = *(const bf16x8*)(kptr + c * 2048 + 32);
            kf2 = *(const bf16x8*)(kptr + c * 2048 + 1024);
            kf3 = *(const bf16x8*)(kptr + c * 2048 + 1056);
            b0 = *(const f32x4*)(fptr + c * 32);
            b1 = *(const f32x4*)(fptr + c * 32 + 16);
        } else {
            const float* ks = Kb + (size_t)(c * 32 + lq) * DN + lg * 8;
            #pragma unroll
            for (int j = 0; j < 8; ++j) {
                kf0[j] = f2bf(ks[j]);            kf1[j] = f2bf(ks[32 + j]);
                kf2[j] = f2bf(ks[16 * DN + j]);  kf3[j] = f2bf(ks[16 * DN + 32 + j]);
            }
            const i32x4 mv0 = *(const i32x4*)(Mb + c * 32 + 4 * lg);
            const i32x4 mv1 = *(const i32x4*)(Mb + c * 32 + 16 + 4 * lg);
            #pragma unroll
            for (int r = 0; r < 4; ++r) {
                b0[r] = mv0[r] ? -BI_L2E : -1e9f;
                b1[r] = mv1[r] ? -BI_L2E : -1e9f;
            }
        }
        f32x4 a0 = {0.f, 0.f, 0.f, 0.f}, a1 = {0.f, 0.f, 0.f, 0.f};
        a0 = __builtin_amdgcn_mfma_f32_16x16x32_bf16(kf0, qf0, a0, 0, 0, 0);
        a0 = __builtin_amdgcn_mfma_f32_16x16x32_bf16(kf1, qf1, a0, 0, 0, 0);
        a1 = __builtin_amdgcn_mfma_f32_16x16x32_bf16(kf2, qf0, a1, 0, 0, 0);
        a1 = __builtin_amdgcn_mfma_f32_16x16x32_bf16(kf3, qf1, a1, 0, 0, 0);
        #pragma unroll
        for (int r = 0; r < 4; ++r) {
            lsum += fast_exp2(fmaf(a0[r], SC_L2E, b0[r]));
            lsum += fast_exp2(fmaf(a1[r], SC_L2E, b1[r]));
        }
    }
    // row q=lq total: reduce over the 4 lanes sharing lq (lg=0..3)
    lsum += __shfl_xor(lsum, 16);
    lsum += __shfl_xor(lsum, 32);
    const float rl = 1.f / lsum;

    // ================= pass B: recompute, store p, PV =================
    const short* vp0 = Vtb + (size_t)(0 * 16 + lq) * SN;
    const short* vp1 = Vtb + (size_t)(1 * 16 + lq) * SN;
    const short* vp2 = Vtb + (size_t)(2 * 16 + lq) * SN;
    const short* vp3 = Vtb + (size_t)(3 * 16 + lq) * SN;
    float* pptr = out_p + (size_t)lq * SN + 4 * lg;

    f32x4 oacc[4];
    #pragma unroll
    for (int nt = 0; nt < 4; ++nt) oacc[nt] = (f32x4){0.f, 0.f, 0.f, 0.f};

    #pragma unroll 2
    for (int c = 0; c < NCHUNK; ++c) {
        bf16x8 kf0, kf1, kf2, kf3;
        f32x4 b0, b1;
        if constexpr (PRE) {
            kf0 = *(const bf16x8*)(kptr + c * 2048);
            kf1 = *(const bf16x8*)(kptr + c * 2048 + 32);
            kf2 = *(const bf16x8*)(kptr + c * 2048 + 1024);
            kf3 = *(const bf16x8*)(kptr + c * 2048 + 1056);
            b0 = *(const f32x4*)(fptr + c * 32);
            b1 = *(const f32x4*)(fptr + c * 32 + 16);
        } else {
            const float* ks = Kb + (size_t)(c * 32 + lq) * DN + lg * 8;
            #pragma unroll
            for (int j = 0; j < 8; ++j) {
                kf0[j] = f2bf(ks[j]);            kf1[j] = f2bf(ks[32 + j]);
                kf2[j] = f2bf(ks[16 * DN + j]);  kf3[j] = f2bf(ks[16 * DN + 32 + j]);
            }
            const i32x4 mv0 = *(const i32x4*)(Mb + c * 32 + 4 * lg);
            const i32x4 mv1 = *(const i32x4*)(Mb + c * 32 + 16 + 4 * lg);
            #pragma unroll
            for (int r = 0; r < 4; ++r) {
                b0[r] = mv0[r] ? -BI_L2E : -1e9f;
                b1[r] = mv1[r] ? -BI_L2E : -1e9f;
            }
        }
        f32x4 a0 = {0.f, 0.f, 0.f, 0.f}, a1 = {0.f, 0.f, 0.f, 0.f};
        a0 = __builtin_amdgcn_mfma_f32_16x16x32_bf16(kf0, qf0, a0, 0, 0, 0);
        a0 = __builtin_amdgcn_mfma_f32_16x16x32_bf16(kf1, qf1, a0, 0, 0, 0);
        a1 = __builtin_amdgcn_mfma_f32_16x16x32_bf16(kf2, qf0, a1, 0, 0, 0);
        a1 = __builtin_amdgcn_mfma_f32_16x16x32_bf16(kf3, qf1, a1, 0, 0, 0);

        float p0[4], p1[4];
        #pragma unroll
        for (int r = 0; r < 4; ++r) {
            p0[r] = fast_exp2(fmaf(a0[r], SC_L2E, b0[r]));
            p1[r] = fast_exp2(fmaf(a1[r], SC_L2E, b1[r]));
        }

        // store p = p~ * rl straight from f32 (plain stores, spread over loop)
        f32x4 o0, o1;
        #pragma unroll
        for (int r = 0; r < 4; ++r) { o0[r] = p0[r] * rl; o1[r] = p1[r] * rl; }
        *(f32x4*)(pptr + c * 32) = o0;
        *(f32x4*)(pptr + c * 32 + 16) = o1;

        // PV: A = packed quads in place (slot-permuted), B = V^T quads at 4lg / 16+4lg
        union { unsigned u[4]; bf16x8 v; } pa;
        pa.u[0] = pk2(p0[0], p0[1]); pa.u[1] = pk2(p0[2], p0[3]);
        pa.u[2] = pk2(p1[0], p1[1]); pa.u[3] = pk2(p1[2], p1[3]);

        union { bf16x4 q[2]; bf16x8 v; } vf0, vf1, vf2, vf3;
        if constexpr (PRE) {
            const int off = c * 32 + 4 * lg;
            vf0.q[0] = *(const bf16x4*)(vp0 + off); vf0.q[1] = *(const bf16x4*)(vp0 + off + 16);
            vf1.q[0] = *(const bf16x4*)(vp1 + off); vf1.q[1] = *(const bf16x4*)(vp1 + off + 16);
            vf2.q[0] = *(const bf16x4*)(vp2 + off); vf2.q[1] = *(const bf16x4*)(vp2 + off + 16);
            vf3.q[0] = *(const bf16x4*)(vp3 + off); vf3.q[1] = *(const bf16x4*)(vp3 + off + 16);
        } else {
            #pragma unroll
            for (int j = 0; j < 4; ++j) {
                const float* va = Vb + (size_t)(c * 32 + 4 * lg + j) * DN + lq;
                const float* vb = Vb + (size_t)(c * 32 + 16 + 4 * lg + j) * DN + lq;
                vf0.v[j] = f2bf(va[0]);  vf0.v[4 + j] = f2bf(vb[0]);
                vf1.v[j] = f2bf(va[16]); vf1.v[4 + j] = f2bf(vb[16]);
                vf2.v[j] = f2bf(va[32]); vf2.v[4 + j] = f2bf(vb[32]);
                vf3.v[j] = f2bf(va[48]); vf3.v[4 + j] = f2bf(vb[48]);
            }
        }
        oacc[0] = __builtin_amdgcn_mfma_f32_16x16x32_bf16(pa.v, vf0.v, oacc[0], 0, 0, 0);
        oacc[1] = __builtin_amdgcn_mfma_f32_16x16x32_bf16(pa.v, vf1.v, oacc[1], 0, 0, 0);
        oacc[2] = __builtin_amdgcn_mfma_f32_16x16x32_bf16(pa.v, vf2.v, oacc[2], 0, 0, 0);
        oacc[3] = __builtin_amdgcn_mfma_f32_16x16x32_bf16(pa.v, vf3.v, oacc[3], 0, 0, 0);
    }

    // ---- O write: oacc[nt][r] = O[q=4lg+r][d=nt*16+lq] * rl(of that row) ----
    // rl is per-row; rows here are 4lg+r, but rl was computed for row lq.
    // Fetch the right rl per output row via shfl from lane holding lq=4lg+r.
    #pragma unroll
    for (int nt = 0; nt < 4; ++nt) {
        #pragma unroll
        for (int r = 0; r < 4; ++r) {
            const float rrow = __shfl(rl, 4 * lg + r);   // lane (lq=4lg+r, lg=0)
            out_o[(size_t)(4 * lg + r) * DN + nt * 16 + lq] = oacc[nt][r] * rrow;
        }
    }
}

extern "C" void kernel_launch(void* const* d_in, const int* in_sizes, int n_in,
                              void* d_out, int out_size, void* d_ws, size_t ws_size,
                              hipStream_t stream) {
    const float* Q = (const float*)d_in[0];
    const float* K = (const float*)d_in[1];
    const float* V = (const float*)d_in[2];
    const int*   M = (const int*)d_in[3];
    float* out = (float*)d_out;
    const size_t half = (size_t)BN * SN * DN;                  // K/V elements
    const size_t need = 2 * half * sizeof(short) + (size_t)BN * SN * sizeof(float);
    dim3 block(256);
    dim3 grid(BN * (SN / QB) / 4);                             // 512 blocks x 4 waves
    if (ws_size >= need) {
        short* Kp = (short*)d_ws;
        short* Vt = Kp + half;
        float* Mf = (float*)(Vt + half);
        prep_kv<<<dim3(BN * (SN / 64)), dim3(256), 0, stream>>>(K, V, M, Kp, Vt, Mf);
        attn_fused<1><<<grid, block, 0, stream>>>(Q, K, V, M, Kp, Vt, Mf, out);
    } else {
        attn_fused<0><<<grid, block, 0, stream>>>(Q, K, V, M, nullptr, nullptr, nullptr, out);
    }
}